// Round 2
// baseline (203.906 us; speedup 1.0000x reference)
//
#include <hip/hip_runtime.h>
#include <hip/hip_bf16.h>

// Algebraic simplification of the reference:
//   softmax rows sum to exactly 1  =>  head_w = attn.sum((0,2)) = N_NODES (all heads)
//   =>  out = (N_NODES * (x @ Wv)) @ w_proj + b_proj
// where Wv[d][h*128+hd] = w_qkv[2][h][d][hd].
// adj, w_q, w_k are mathematically irrelevant to the output and never read.
// ALL tensors are fp32 (reference dtypes; R1 NaN showed bf16 reinterpretation
// of fp32 buffers — mantissa halves decode as bf16 NaNs).

constexpr int N_NODES = 4096;
constexpr int DIM = 512;       // INPUT_DIM == OUTPUT_DIM == 512
constexpr int HEADS = 4;
constexpr int HD = 128;

// ---------------------------------------------------------------------------
// Kernel A: M[d][o] = N_NODES * sum_c Wv[d][c] * w_proj[c][o]   (fp32 in d_ws)
// One thread per output element; within a wave d is uniform, o coalesced.
// ---------------------------------------------------------------------------
__global__ __launch_bounds__(256) void build_M(
    const float* __restrict__ w_qkv,
    const float* __restrict__ w_proj,
    float* __restrict__ M) {
  const int t = blockIdx.x * 256 + threadIdx.x;   // 512*512 threads
  const int d = t >> 9;
  const int o = t & (DIM - 1);
  const float* __restrict__ wv = w_qkv + 2 * HEADS * DIM * HD;  // v slice
  float acc = 0.f;
  for (int h = 0; h < HEADS; ++h) {
    const float* __restrict__ wvrow = wv + (h * DIM + d) * HD;
#pragma unroll 8
    for (int hd = 0; hd < HD; ++hd) {
      const float a = wvrow[hd];                       // wave-uniform (scalar load)
      const float b = w_proj[(h * HD + hd) * DIM + o]; // coalesced
      acc = fmaf(a, b, acc);
    }
  }
  M[d * DIM + o] = acc * (float)N_NODES;
}

// ---------------------------------------------------------------------------
// Kernel B: out[b][o] = sum_d x[b][d] * M[d][o] + b_proj[o]    (fp32 out)
// 64x64 tile per block, BK=32, 256 threads, 4x4 micro-tile each, fp32 acc.
// ---------------------------------------------------------------------------
__global__ __launch_bounds__(256) void gemm_out(
    const float* __restrict__ x,
    const float* __restrict__ M,
    const float* __restrict__ bias,
    float* __restrict__ out) {
  __shared__ float xs[64][33];   // +1 pad: conflict-free column reads
  __shared__ float ms[32][65];
  const int bm = blockIdx.y * 64;
  const int bn = blockIdx.x * 64;
  const int tid = threadIdx.x;
  const int tr = (tid >> 4) * 4;   // 0..60
  const int tc = (tid & 15) * 4;   // 0..60

  float acc[4][4] = {};

  for (int k0 = 0; k0 < DIM; k0 += 32) {
    // stage x tile 64x32 (2048 elems, 8 per thread), coalesced
#pragma unroll
    for (int i = tid; i < 64 * 32; i += 256) {
      const int r = i >> 5, c = i & 31;
      xs[r][c] = x[(bm + r) * DIM + (k0 + c)];
    }
    // stage M tile 32x64
#pragma unroll
    for (int i = tid; i < 32 * 64; i += 256) {
      const int r = i >> 6, c = i & 63;
      ms[r][c] = M[(k0 + r) * DIM + (bn + c)];
    }
    __syncthreads();

#pragma unroll
    for (int k = 0; k < 32; ++k) {
      float a[4], b[4];
#pragma unroll
      for (int i = 0; i < 4; ++i) a[i] = xs[tr + i][k];
#pragma unroll
      for (int j = 0; j < 4; ++j) b[j] = ms[k][tc + j];
#pragma unroll
      for (int i = 0; i < 4; ++i)
#pragma unroll
        for (int j = 0; j < 4; ++j)
          acc[i][j] = fmaf(a[i], b[j], acc[i][j]);
    }
    __syncthreads();
  }

#pragma unroll
  for (int j = 0; j < 4; ++j) {
    const float bj = bias[bn + tc + j];
#pragma unroll
    for (int i = 0; i < 4; ++i) {
      out[(bm + tr + i) * DIM + (bn + tc + j)] = acc[i][j] + bj;
    }
  }
}

extern "C" void kernel_launch(void* const* d_in, const int* in_sizes, int n_in,
                              void* d_out, int out_size, void* d_ws, size_t ws_size,
                              hipStream_t stream) {
  const float* x      = (const float*)d_in[0];
  // d_in[1] = adj — mathematically irrelevant (softmax rows sum to 1), never read
  const float* w_qkv  = (const float*)d_in[2];
  const float* w_proj = (const float*)d_in[3];
  const float* b_proj = (const float*)d_in[4];
  float* M = (float*)d_ws;                 // 512*512*4 = 1 MB scratch
  float* out = (float*)d_out;              // 4096*512 fp32

  build_M<<<dim3((DIM * DIM) / 256), 256, 0, stream>>>(w_qkv, w_proj, M);
  gemm_out<<<dim3(DIM / 64, N_NODES / 64), 256, 0, stream>>>(x, M, b_proj, out);
}